// Round 1
// baseline (294.476 us; speedup 1.0000x reference)
//
#include <hip/hip_runtime.h>

// CrossJointAttention fused kernel for MI355X (gfx950).
// B=16384 batches, N=12 joints, D=128, H=4 heads, hd=32. fp32 in/out,
// bf16 MFMA (16x16x32) internally.
//
// One workgroup = 4 batches (48 joint-rows), 256 threads (4 waves).
// LDS ~79KB -> 2 WG/CU. Grid = 4096 WGs.
//
// Layout trick: Q/K GEMMs run in transposed form (C = W * x^T) so the cheap
// MFMA C-store (lane holds 4 consecutive rows of one column) writes q,k
// row-major [joint][feat] -- the exact A/B fragment layout for the scores
// MFMA. V runs in normal form so its cheap store lands v^T[feat][joint],
// the A layout for ctx^T = v^T * P^T, whose cheap store lands ctx row-major
// [joint][feat] feeding the O-projection. All fragment reads are contiguous.

typedef unsigned short u16;
typedef short bf16x8 __attribute__((ext_vector_type(8)));   // 8 bf16 = 4 VGPRs
typedef float f32x4 __attribute__((ext_vector_type(4)));

#define MFMA(a, b, c) __builtin_amdgcn_mfma_f32_16x16x32_bf16((a), (b), (c), 0, 0, 0)

#define BPW   4            // batches per workgroup
#define ROWS  (BPW * 12)   // 48 joint-rows per WG
#define XPAD  136          // row stride (bf16 elems) for x/q/k/ctx: 272B -> even bank spread

struct SMem {
    u16   xs[ROWS * XPAD];      // staged x (bf16); later overlaid with ctx
    u16   qs[ROWS * XPAD];      // q row-major [joint-row][feat]
    u16   ks[ROWS * XPAD];      // k row-major [joint-row][feat]
    u16   vT[BPW * 128 * 32];   // v^T per batch: [feat][joint(pad 32)]
    u16   P[4 * 16 * 32];       // per-wave softmax probs [n][m(pad 32)]
    float bias_s[16 * 16];      // adjacency*bias_scale, -1e30 padding (mask)
    float vis_s[BPW * 16];      // visibility per (batch, key joint)
    float bvec[4 * 128];        // bq | bk | bv | bo
};

__device__ __forceinline__ u16 f2b(float f) {   // fp32 -> bf16 RNE
    unsigned u = __builtin_bit_cast(unsigned, f);
    return (u16)((u + 0x7fffu + ((u >> 16) & 1u)) >> 16);
}

__device__ __forceinline__ void st4(u16* p, float a, float b, float c, float d) {
    ushort4 v; v.x = f2b(a); v.y = f2b(b); v.z = f2b(c); v.w = f2b(d);
    *(ushort4*)p = v;   // ds_write_b64
}

__global__ void prep_w(const float* __restrict__ Wq, const float* __restrict__ Wk,
                       const float* __restrict__ Wv, const float* __restrict__ Wo,
                       u16* __restrict__ wbf) {
    int i = blockIdx.x * 256 + threadIdx.x;     // 0..16383
    wbf[i]         = f2b(Wq[i]);
    wbf[16384 + i] = f2b(Wk[i]);
    wbf[32768 + i] = f2b(Wv[i]);
    wbf[49152 + i] = f2b(Wo[i]);
}

__global__ __launch_bounds__(256, 2) void cja_main(
    const float* __restrict__ x, const float* __restrict__ vis,
    const float* __restrict__ bq, const float* __restrict__ bk,
    const float* __restrict__ bv, const float* __restrict__ bo,
    const float* __restrict__ bias_scale, const float* __restrict__ adj,
    const u16* __restrict__ wbf, float* __restrict__ out)
{
    extern __shared__ char smraw[];
    SMem& sm = *(SMem*)smraw;

    const int tid  = threadIdx.x;
    const int wave = tid >> 6;
    const int lane = tid & 63;
    const int lq   = lane >> 4;      // quadrant 0..3
    const int lm   = lane & 15;      // 0..15
    const int b0   = blockIdx.x * BPW;

    // ---------------- Phase 0: stage x (fp32->bf16), masks, biases ----------
    for (int i = tid; i < ROWS * 32; i += 256) {          // 6 iters: float4 chunks
        int row = i >> 5, c4 = (i & 31) << 2;
        float4 v = *(const float4*)(x + ((size_t)(b0 * 12 + row) << 7) + c4);
        st4(sm.xs + row * XPAD + c4, v.x, v.y, v.z, v.w);
    }
    for (int i = tid; i < BPW * 128; i += 256) {          // zero vT pad cols 12..31
        unsigned* d = (unsigned*)(sm.vT + i * 32 + 12);   // 24B offset: 4B aligned
        #pragma unroll
        for (int j = 0; j < 10; j++) d[j] = 0u;
    }
    if (tid < 64) {                                        // zero P pad cols 16..31
        unsigned* d = (unsigned*)(sm.P + tid * 32 + 16);
        #pragma unroll
        for (int j = 0; j < 8; j++) d[j] = 0u;
    }
    {
        float scale = bias_scale[0];
        int n = tid >> 4, m = tid & 15;
        float bval = -1e30f;                               // masks key pads m>=12
        if (n < 12 && m < 12) bval = adj[n * 12 + m] * scale;
        sm.bias_s[tid] = bval;
        if (tid < BPW * 16) {
            int bb = tid >> 4, mm = tid & 15;
            sm.vis_s[tid] = (mm < 12) ? vis[(size_t)(b0 + bb) * 12 + mm] : 1.0f;
        }
        if (tid < 128) {
            sm.bvec[tid]       = bq[tid];
            sm.bvec[128 + tid] = bk[tid];
            sm.bvec[256 + tid] = bv[tid];
            sm.bvec[384 + tid] = bo[tid];
        }
    }
    __syncthreads();

    // ---------------- Phase 1: fused Q/K/V GEMMs ----------------------------
    {
        const u16* Wq_b = wbf;
        const u16* Wk_b = wbf + 16384;
        const u16* Wv_b = wbf + 32768;
        f32x4 accq[2][3], acck[2][3], accv[3][2];
        #pragma unroll
        for (int i = 0; i < 2; i++)
            #pragma unroll
            for (int j = 0; j < 3; j++) { accq[i][j] = (f32x4){0,0,0,0}; acck[i][j] = (f32x4){0,0,0,0}; }
        #pragma unroll
        for (int i = 0; i < 3; i++)
            #pragma unroll
            for (int j = 0; j < 2; j++) accv[i][j] = (f32x4){0,0,0,0};

        const int mrow0 = (wave * 2) * 16 + lm;   // weight row (feature)
        const int mrow1 = mrow0 + 16;
        #pragma unroll
        for (int ks = 0; ks < 4; ks++) {
            const int koff = ks * 32 + lq * 8;
            bf16x8 xf[3];
            #pragma unroll
            for (int nt = 0; nt < 3; nt++)
                xf[nt] = *(const bf16x8*)(sm.xs + (nt * 16 + lm) * XPAD + koff);
            bf16x8 wq0 = *(const bf16x8*)(Wq_b + mrow0 * 128 + koff);
            bf16x8 wq1 = *(const bf16x8*)(Wq_b + mrow1 * 128 + koff);
            bf16x8 wk0 = *(const bf16x8*)(Wk_b + mrow0 * 128 + koff);
            bf16x8 wk1 = *(const bf16x8*)(Wk_b + mrow1 * 128 + koff);
            bf16x8 wv0 = *(const bf16x8*)(Wv_b + mrow0 * 128 + koff);
            bf16x8 wv1 = *(const bf16x8*)(Wv_b + mrow1 * 128 + koff);
            #pragma unroll
            for (int nt = 0; nt < 3; nt++) {
                accq[0][nt] = MFMA(wq0, xf[nt], accq[0][nt]);   // C[e,n] = Wq . x^T
                accq[1][nt] = MFMA(wq1, xf[nt], accq[1][nt]);
                acck[0][nt] = MFMA(wk0, xf[nt], acck[0][nt]);
                acck[1][nt] = MFMA(wk1, xf[nt], acck[1][nt]);
                accv[nt][0] = MFMA(xf[nt], wv0, accv[nt][0]);   // C[n,e] = x . Wv^T
                accv[nt][1] = MFMA(xf[nt], wv1, accv[nt][1]);
            }
        }
        // epilogue Q/K: transposed store -> q,k row-major [joint-row][feat]
        #pragma unroll
        for (int mi = 0; mi < 2; mi++) {
            const int e0 = (wave * 2 + mi) * 16 + lq * 4;
            float bq0 = sm.bvec[e0], bq1 = sm.bvec[e0+1], bq2 = sm.bvec[e0+2], bq3 = sm.bvec[e0+3];
            float bk0 = sm.bvec[128+e0], bk1 = sm.bvec[128+e0+1], bk2 = sm.bvec[128+e0+2], bk3 = sm.bvec[128+e0+3];
            #pragma unroll
            for (int nt = 0; nt < 3; nt++) {
                const int n = nt * 16 + lm;                   // joint-row 0..47
                st4(sm.qs + n * XPAD + e0, accq[mi][nt][0]+bq0, accq[mi][nt][1]+bq1,
                                           accq[mi][nt][2]+bq2, accq[mi][nt][3]+bq3);
                st4(sm.ks + n * XPAD + e0, acck[mi][nt][0]+bk0, acck[mi][nt][1]+bk1,
                                           acck[mi][nt][2]+bk2, acck[mi][nt][3]+bk3);
            }
        }
        // epilogue V: transposed scatter -> vT[batch][feat][joint]
        #pragma unroll
        for (int nt2 = 0; nt2 < 2; nt2++) {
            const int e = (wave * 2 + nt2) * 16 + lm;         // feature column
            const float bvv = sm.bvec[256 + e];
            #pragma unroll
            for (int mt = 0; mt < 3; mt++) {
                #pragma unroll
                for (int r = 0; r < 4; r++) {
                    int n = mt * 16 + lq * 4 + r;             // joint-row 0..47
                    int bb = n / 12, j = n - bb * 12;
                    sm.vT[bb * 4096 + e * 32 + j] = f2b(accv[mt][nt2][r] + bvv);
                }
            }
        }
    }
    __syncthreads();

    // ---------------- Phase 2: attention (wave w owns batch w) --------------
    {
        const int bl = wave;
        const int nql  = (lm < 12) ? lm : 11;                 // clamp: no OOB reads
        const int qrow = (bl * 12 + nql) * XPAD;
        const float vism = 10.0f * (1.0f - sm.vis_s[bl * 16 + lm]);
        u16* Pw = sm.P + wave * 512;
        #pragma unroll
        for (int h = 0; h < 4; h++) {
            bf16x8 qa = *(const bf16x8*)(sm.qs + qrow + h * 32 + lq * 8);
            bf16x8 kb = *(const bf16x8*)(sm.ks + qrow + h * 32 + lq * 8);
            f32x4 sc = (f32x4){0,0,0,0};
            sc = MFMA(qa, kb, sc);                            // scores[n,m], K=hd=32
            float p[4];
            #pragma unroll
            for (int r = 0; r < 4; r++) {
                const int n = lq * 4 + r;
                float s = sc[r] * 0.17677669529663689f + sm.bias_s[n * 16 + lm] - vism;
                float mx = s;
                mx = fmaxf(mx, __shfl_xor(mx, 1, 16));
                mx = fmaxf(mx, __shfl_xor(mx, 2, 16));
                mx = fmaxf(mx, __shfl_xor(mx, 4, 16));
                mx = fmaxf(mx, __shfl_xor(mx, 8, 16));
                float e = __expf(s - mx);
                float l = e;
                l += __shfl_xor(l, 1, 16);
                l += __shfl_xor(l, 2, 16);
                l += __shfl_xor(l, 4, 16);
                l += __shfl_xor(l, 8, 16);
                p[r] = e / l;
            }
            #pragma unroll
            for (int r = 0; r < 4; r++)                        // P row-major [n][m]
                Pw[(lq * 4 + r) * 32 + lm] = (lm < 12) ? f2b(p[r]) : (u16)0;
            // ctx^T = v^T . P^T : C[e', n] ; cheap store -> ctx row-major in xs
            #pragma unroll
            for (int mt = 0; mt < 2; mt++) {
                bf16x8 va = *(const bf16x8*)(sm.vT + bl * 4096 + (h * 32 + mt * 16 + lm) * 32 + lq * 8);
                bf16x8 pb = *(const bf16x8*)(Pw + lm * 32 + lq * 8);
                f32x4 c = (f32x4){0,0,0,0};
                c = MFMA(va, pb, c);
                if (lm < 12) {
                    u16* d = sm.xs + (bl * 12 + lm) * XPAD + h * 32 + mt * 16 + lq * 4;
                    st4(d, c[0], c[1], c[2], c[3]);
                }
            }
        }
    }
    __syncthreads();

    // ---------------- Phase 3: output projection (transposed form) ----------
    {
        const u16* Wo_b = wbf + 49152;
        f32x4 acc[2][3];
        #pragma unroll
        for (int i = 0; i < 2; i++)
            #pragma unroll
            for (int j = 0; j < 3; j++) acc[i][j] = (f32x4){0,0,0,0};
        const int m0 = (wave * 2) * 16 + lm;
        #pragma unroll
        for (int ks = 0; ks < 4; ks++) {
            const int koff = ks * 32 + lq * 8;
            bf16x8 a0 = *(const bf16x8*)(Wo_b + m0 * 128 + koff);
            bf16x8 a1 = *(const bf16x8*)(Wo_b + (m0 + 16) * 128 + koff);
            #pragma unroll
            for (int nt = 0; nt < 3; nt++) {
                bf16x8 bfr = *(const bf16x8*)(sm.xs + (nt * 16 + lm) * XPAD + koff);
                acc[0][nt] = MFMA(a0, bfr, acc[0][nt]);
                acc[1][nt] = MFMA(a1, bfr, acc[1][nt]);
            }
        }
        #pragma unroll
        for (int mi = 0; mi < 2; mi++) {
            const int e0 = (wave * 2 + mi) * 16 + lq * 4;
            float bo0 = sm.bvec[384+e0], bo1 = sm.bvec[384+e0+1],
                  bo2 = sm.bvec[384+e0+2], bo3 = sm.bvec[384+e0+3];
            #pragma unroll
            for (int nt = 0; nt < 3; nt++) {
                const int n = nt * 16 + lm;                    // joint-row 0..47
                float4 o;
                o.x = acc[mi][nt][0] + bo0;
                o.y = acc[mi][nt][1] + bo1;
                o.z = acc[mi][nt][2] + bo2;
                o.w = acc[mi][nt][3] + bo3;
                *(float4*)(out + ((size_t)(b0 * 12 + n) << 7) + e0) = o;
            }
        }
    }
}

extern "C" void kernel_launch(void* const* d_in, const int* in_sizes, int n_in,
                              void* d_out, int out_size, void* d_ws, size_t ws_size,
                              hipStream_t stream) {
    const float* x   = (const float*)d_in[0];
    const float* vis = (const float*)d_in[1];
    const float* Wq  = (const float*)d_in[2];
    const float* bq  = (const float*)d_in[3];
    const float* Wk  = (const float*)d_in[4];
    const float* bk  = (const float*)d_in[5];
    const float* Wv  = (const float*)d_in[6];
    const float* bv  = (const float*)d_in[7];
    const float* Wo  = (const float*)d_in[8];
    const float* bo  = (const float*)d_in[9];
    const float* bs  = (const float*)d_in[10];
    const float* adj = (const float*)d_in[11];
    u16* wbf = (u16*)d_ws;   // 4 x 128x128 bf16 = 128KB

    prep_w<<<64, 256, 0, stream>>>(Wq, Wk, Wv, Wo, wbf);
    cja_main<<<16384 / BPW, 256, sizeof(SMem), stream>>>(
        x, vis, bq, bk, bv, bo, bs, adj, wbf, (float*)d_out);
}

// Round 2
// 287.235 us; speedup vs baseline: 1.0252x; 1.0252x over previous
//
#include <hip/hip_runtime.h>

// CrossJointAttention fused kernel for MI355X (gfx950) -- Round 2.
// B=16384, N=12 joints, D=128, H=4, hd=32. fp32 in/out, bf16 MFMA internally.
//
// R2 changes vs R1 (which was latency-bound: 21.6% occupancy, 20% of cycles
// in LDS bank conflicts):
//  - no xs staging: phase-1 x fragments loaded straight from global (L2-hot),
//    removing phase 0 and 13KB LDS.
//  - vT/P row stride = 20 elems (10 words, odd*2) -> fragment reads and the
//    v^T scatter are <=2-way bank conflicts (free) vs 16-way before.
//  - PV via 16x16x32 MFMA with quads 2..3 zero-masked (K-extent 16); all
//    LDS fragment loads are 8B-aligned ds_read_b64 pairs.
//  - softmax: no max-sub (scores bounded), exp2-prescaled constants,
//    unnormalized P with 1/l folded into ctx epilogue -> half the shuffles.
//  - ctx overlays qs (per-head column reuse, wave-local).
//  - LDS 52.7KB -> 3 WG/CU (was 2), __launch_bounds__(256,3).

typedef unsigned short u16;
typedef short bf16x8 __attribute__((ext_vector_type(8)));   // 8 bf16 = 4 VGPRs
typedef short bf16x4 __attribute__((ext_vector_type(4)));   // 4 bf16 = 2 VGPRs
typedef float f32x4 __attribute__((ext_vector_type(4)));

#define MFMA(a, b, c) __builtin_amdgcn_mfma_f32_16x16x32_bf16((a), (b), (c), 0, 0, 0)

#define BPW   4            // batches per workgroup
#define ROWS  (BPW * 12)   // 48 joint-rows per WG
#define XPAD  136          // row stride (bf16) for q/k/ctx: 272B, 16B-aligned
#define VPAD  20           // vT row stride: 40B -> bank coeff 10 (odd*2), 8B-aligned
#define PPAD  20           // P row stride

struct SMem {
    u16   qs[ROWS * XPAD];       // q rows [48][128]; ctx overlays per-head
    u16   ks[ROWS * XPAD];       // k rows
    u16   vT[BPW * 128 * VPAD];  // per batch [feat][joint pad 20]
    u16   P[4 * 16 * PPAD];      // per wave unnormalized exp [n][m pad 20]
    float bias_s[16 * 16];       // adj*scale*log2e; -1e30 for m>=12; 0 for n>=12
    float vis_s[BPW * 16];       // 10*(1-vis)*log2e; 0 for pad
    float bvec[4 * 128];         // bq | bk | bv | bo
    float rls[4 * 16];           // per wave: 1/rowsum for each n
};

__device__ __forceinline__ u16 f2b(float f) {   // fp32 -> bf16 RNE
    unsigned u = __builtin_bit_cast(unsigned, f);
    return (u16)((u + 0x7fffu + ((u >> 16) & 1u)) >> 16);
}

__device__ __forceinline__ void st4(u16* p, float a, float b, float c, float d) {
    ushort4 v; v.x = f2b(a); v.y = f2b(b); v.z = f2b(c); v.w = f2b(d);
    *(ushort4*)p = v;   // ds_write_b64
}

__device__ __forceinline__ bf16x8 pack8(float4 a, float4 b) {
    bf16x8 r;
    r[0] = (short)f2b(a.x); r[1] = (short)f2b(a.y);
    r[2] = (short)f2b(a.z); r[3] = (short)f2b(a.w);
    r[4] = (short)f2b(b.x); r[5] = (short)f2b(b.y);
    r[6] = (short)f2b(b.z); r[7] = (short)f2b(b.w);
    return r;
}

__global__ void prep_w(const float* __restrict__ Wq, const float* __restrict__ Wk,
                       const float* __restrict__ Wv, const float* __restrict__ Wo,
                       u16* __restrict__ wbf) {
    int i = blockIdx.x * 256 + threadIdx.x;     // 0..16383
    wbf[i]         = f2b(Wq[i]);
    wbf[16384 + i] = f2b(Wk[i]);
    wbf[32768 + i] = f2b(Wv[i]);
    wbf[49152 + i] = f2b(Wo[i]);
}

__global__ __launch_bounds__(256, 3) void cja_main(
    const float* __restrict__ x, const float* __restrict__ vis,
    const float* __restrict__ bq, const float* __restrict__ bk,
    const float* __restrict__ bv, const float* __restrict__ bo,
    const float* __restrict__ bias_scale, const float* __restrict__ adj,
    const u16* __restrict__ wbf, float* __restrict__ out)
{
    extern __shared__ char smraw[];
    SMem& sm = *(SMem*)smraw;

    const int tid  = threadIdx.x;
    const int wave = tid >> 6;
    const int lane = tid & 63;
    const int lq   = lane >> 4;      // quadrant 0..3
    const int lm   = lane & 15;      // 0..15
    const int b0   = blockIdx.x * BPW;

    // ---------------- Prologue: pads, masks, biases -------------------------
    for (int i = tid; i < BPW * 128; i += 256) {          // zero vT cols 12..19
        unsigned* d = (unsigned*)(sm.vT + i * VPAD + 12); // byte 40i+24: 8B-aligned
        d[0] = 0u; d[1] = 0u; d[2] = 0u; d[3] = 0u;
    }
    {
        const float L2E = 1.4426950408889634f;
        float scale = bias_scale[0] * L2E;
        int n = tid >> 4, m = tid & 15;
        float bval;
        if (m >= 12)     bval = -1e30f;                   // key-pad mask (exp2 -> 0)
        else if (n < 12) bval = adj[n * 12 + m] * scale;
        else             bval = 0.0f;                     // row pad: keep finite
        sm.bias_s[tid] = bval;
        if (tid < BPW * 16) {
            int bb = tid >> 4, mm = tid & 15;
            sm.vis_s[tid] = (mm < 12) ? 10.0f * L2E * (1.0f - vis[(size_t)(b0 + bb) * 12 + mm])
                                      : 0.0f;
        }
        if (tid < 128) {
            sm.bvec[tid]       = bq[tid];
            sm.bvec[128 + tid] = bk[tid];
            sm.bvec[256 + tid] = bv[tid];
            sm.bvec[384 + tid] = bo[tid];
        }
    }
    __syncthreads();

    // ---------------- Phase 1: fused Q/K/V GEMMs (x from global) ------------
    {
        const u16* Wq_b = wbf;
        const u16* Wk_b = wbf + 16384;
        const u16* Wv_b = wbf + 32768;
        const float* xw = x + (size_t)b0 * 1536;   // 12*128 per batch
        f32x4 accq[2][3], acck[2][3], accv[3][2];
        #pragma unroll
        for (int i = 0; i < 2; i++)
            #pragma unroll
            for (int j = 0; j < 3; j++) { accq[i][j] = (f32x4){0,0,0,0}; acck[i][j] = (f32x4){0,0,0,0}; }
        #pragma unroll
        for (int i = 0; i < 3; i++)
            #pragma unroll
            for (int j = 0; j < 2; j++) accv[i][j] = (f32x4){0,0,0,0};

        const int mrow0 = wave * 32 + lm;          // weight row (feature)
        const int mrow1 = mrow0 + 16;
        #pragma unroll
        for (int ks2 = 0; ks2 < 4; ks2++) {
            const int koff = ks2 * 32 + lq * 8;
            bf16x8 xf[3];
            #pragma unroll
            for (int nt = 0; nt < 3; nt++) {
                const float* xp = xw + (nt * 16 + lm) * 128 + koff;
                float4 u0 = *(const float4*)xp;
                float4 u1 = *(const float4*)(xp + 4);
                xf[nt] = pack8(u0, u1);
            }
            bf16x8 wq0 = *(const bf16x8*)(Wq_b + mrow0 * 128 + koff);
            bf16x8 wq1 = *(const bf16x8*)(Wq_b + mrow1 * 128 + koff);
            bf16x8 wk0 = *(const bf16x8*)(Wk_b + mrow0 * 128 + koff);
            bf16x8 wk1 = *(const bf16x8*)(Wk_b + mrow1 * 128 + koff);
            bf16x8 wv0 = *(const bf16x8*)(Wv_b + mrow0 * 128 + koff);
            bf16x8 wv1 = *(const bf16x8*)(Wv_b + mrow1 * 128 + koff);
            #pragma unroll
            for (int nt = 0; nt < 3; nt++) {
                accq[0][nt] = MFMA(wq0, xf[nt], accq[0][nt]);   // C[e,n] = Wq . x^T
                accq[1][nt] = MFMA(wq1, xf[nt], accq[1][nt]);
                acck[0][nt] = MFMA(wk0, xf[nt], acck[0][nt]);
                acck[1][nt] = MFMA(wk1, xf[nt], acck[1][nt]);
                accv[nt][0] = MFMA(xf[nt], wv0, accv[nt][0]);   // C[n,e] = x . Wv^T
                accv[nt][1] = MFMA(xf[nt], wv1, accv[nt][1]);
            }
        }
        // epilogue Q/K: transposed store -> q,k row-major [joint-row][feat]
        #pragma unroll
        for (int mi = 0; mi < 2; mi++) {
            const int e0 = (wave * 2 + mi) * 16 + lq * 4;
            float bq0 = sm.bvec[e0], bq1 = sm.bvec[e0+1], bq2 = sm.bvec[e0+2], bq3 = sm.bvec[e0+3];
            float bk0 = sm.bvec[128+e0], bk1 = sm.bvec[128+e0+1], bk2 = sm.bvec[128+e0+2], bk3 = sm.bvec[128+e0+3];
            #pragma unroll
            for (int nt = 0; nt < 3; nt++) {
                const int n = nt * 16 + lm;                   // joint-row 0..47
                st4(sm.qs + n * XPAD + e0, accq[mi][nt][0]+bq0, accq[mi][nt][1]+bq1,
                                           accq[mi][nt][2]+bq2, accq[mi][nt][3]+bq3);
                st4(sm.ks + n * XPAD + e0, acck[mi][nt][0]+bk0, acck[mi][nt][1]+bk1,
                                           acck[mi][nt][2]+bk2, acck[mi][nt][3]+bk3);
            }
        }
        // epilogue V: scatter -> vT[batch][feat][joint], stride 20 (conflict-free)
        #pragma unroll
        for (int nt2 = 0; nt2 < 2; nt2++) {
            const int e = (wave * 2 + nt2) * 16 + lm;         // feature column
            const float bvv = sm.bvec[256 + e];
            #pragma unroll
            for (int mt = 0; mt < 3; mt++) {
                #pragma unroll
                for (int r = 0; r < 4; r++) {
                    int n = mt * 16 + lq * 4 + r;             // joint-row 0..47
                    int bb = n / 12, j = n - bb * 12;
                    sm.vT[bb * (128 * VPAD) + e * VPAD + j] = f2b(accv[mt][nt2][r] + bvv);
                }
            }
        }
    }
    __syncthreads();

    // ---------------- Phase 2: attention (wave w owns batch w) --------------
    {
        const int bl   = wave;
        const int nql  = (lm < 12) ? lm : 11;                 // clamp: no OOB reads
        const u16* qrowp = sm.qs + (bl * 12 + nql) * XPAD;
        const u16* krowp = sm.ks + (bl * 12 + nql) * XPAD;
        const float vism = sm.vis_s[bl * 16 + lm];
        float bias_b[4];
        #pragma unroll
        for (int r = 0; r < 4; r++) bias_b[r] = sm.bias_s[(lq * 4 + r) * 16 + lm];
        u16*   Pw  = sm.P + wave * (16 * PPAD);
        float* rlw = sm.rls + wave * 16;
        const u16* vTb = sm.vT + bl * (128 * VPAD);
        const float SC2 = 0.2550348606381560f;                // (1/sqrt(32))*log2(e)
        const bf16x8 z8 = {0,0,0,0,0,0,0,0};
        #pragma unroll
        for (int h = 0; h < 4; h++) {
            bf16x8 qa = *(const bf16x8*)(qrowp + h * 32 + lq * 8);
            bf16x8 kb = *(const bf16x8*)(krowp + h * 32 + lq * 8);
            f32x4 sc = MFMA(qa, kb, ((f32x4){0,0,0,0}));      // scores[n,m]
            #pragma unroll
            for (int r = 0; r < 4; r++) {
                float s2 = sc[r] * SC2 + bias_b[r] - vism;    // base-2 domain
                float e  = __builtin_amdgcn_exp2f(s2);        // 0 exactly for pads
                float l  = e;
                l += __shfl_xor(l, 1, 16);
                l += __shfl_xor(l, 2, 16);
                l += __shfl_xor(l, 4, 16);
                l += __shfl_xor(l, 8, 16);
                Pw[(lq * 4 + r) * PPAD + lm] = f2b(e);        // unnormalized
                if (lm == 0) rlw[lq * 4 + r] = __builtin_amdgcn_rcpf(l);
            }
            float rln = rlw[lm];                              // 1/l for col n=lm
            bf16x8 pb = z8;                                   // quads 2,3 = zero (K-ext 16)
            if (lq < 2) {
                const bf16x4* pp = (const bf16x4*)(Pw + lm * PPAD + lq * 8);
                pb = __builtin_shufflevector(pp[0], pp[1], 0, 1, 2, 3, 4, 5, 6, 7);
            }
            #pragma unroll
            for (int mt = 0; mt < 2; mt++) {
                bf16x8 va = z8;
                if (lq < 2) {
                    const bf16x4* vp = (const bf16x4*)(vTb + (h * 32 + mt * 16 + lm) * VPAD + lq * 8);
                    va = __builtin_shufflevector(vp[0], vp[1], 0, 1, 2, 3, 4, 5, 6, 7);
                }
                f32x4 c = MFMA(va, pb, ((f32x4){0,0,0,0}));   // C[e',n]
                if (lm < 12) {                                 // ctx overlays qs
                    u16* d = sm.qs + (bl * 12 + lm) * XPAD + h * 32 + mt * 16 + lq * 4;
                    st4(d, c[0] * rln, c[1] * rln, c[2] * rln, c[3] * rln);
                }
            }
        }
    }
    __syncthreads();

    // ---------------- Phase 3: output projection (transposed form) ----------
    {
        const u16* Wo_b = wbf + 49152;
        f32x4 acc[2][3];
        #pragma unroll
        for (int i = 0; i < 2; i++)
            #pragma unroll
            for (int j = 0; j < 3; j++) acc[i][j] = (f32x4){0,0,0,0};
        const int m0 = wave * 32 + lm;
        #pragma unroll
        for (int ks2 = 0; ks2 < 4; ks2++) {
            const int koff = ks2 * 32 + lq * 8;
            bf16x8 a0 = *(const bf16x8*)(Wo_b + m0 * 128 + koff);
            bf16x8 a1 = *(const bf16x8*)(Wo_b + (m0 + 16) * 128 + koff);
            #pragma unroll
            for (int nt = 0; nt < 3; nt++) {
                bf16x8 bfr = *(const bf16x8*)(sm.qs + (nt * 16 + lm) * XPAD + koff);
                acc[0][nt] = MFMA(a0, bfr, acc[0][nt]);
                acc[1][nt] = MFMA(a1, bfr, acc[1][nt]);
            }
        }
        #pragma unroll
        for (int mi = 0; mi < 2; mi++) {
            const int e0 = (wave * 2 + mi) * 16 + lq * 4;
            float bo0 = sm.bvec[384+e0], bo1 = sm.bvec[384+e0+1],
                  bo2 = sm.bvec[384+e0+2], bo3 = sm.bvec[384+e0+3];
            #pragma unroll
            for (int nt = 0; nt < 3; nt++) {
                const int n = nt * 16 + lm;                    // joint-row 0..47
                float4 o;
                o.x = acc[mi][nt][0] + bo0;
                o.y = acc[mi][nt][1] + bo1;
                o.z = acc[mi][nt][2] + bo2;
                o.w = acc[mi][nt][3] + bo3;
                *(float4*)(out + ((size_t)(b0 * 12 + n) << 7) + e0) = o;
            }
        }
    }
}

extern "C" void kernel_launch(void* const* d_in, const int* in_sizes, int n_in,
                              void* d_out, int out_size, void* d_ws, size_t ws_size,
                              hipStream_t stream) {
    const float* x   = (const float*)d_in[0];
    const float* vis = (const float*)d_in[1];
    const float* Wq  = (const float*)d_in[2];
    const float* bq  = (const float*)d_in[3];
    const float* Wk  = (const float*)d_in[4];
    const float* bk  = (const float*)d_in[5];
    const float* Wv  = (const float*)d_in[6];
    const float* bv  = (const float*)d_in[7];
    const float* Wo  = (const float*)d_in[8];
    const float* bo  = (const float*)d_in[9];
    const float* bs  = (const float*)d_in[10];
    const float* adj = (const float*)d_in[11];
    u16* wbf = (u16*)d_ws;   // 4 x 128x128 bf16 = 128KB

    prep_w<<<64, 256, 0, stream>>>(Wq, Wk, Wv, Wo, wbf);
    cja_main<<<16384 / BPW, 256, sizeof(SMem), stream>>>(
        x, vis, bq, bk, bv, bo, bs, adj, wbf, (float*)d_out);
}